// Round 6
// baseline (6543.644 us; speedup 1.0000x reference)
//
#include <hip/hip_runtime.h>
#include <hip/hip_bf16.h>
#include <cstdint>

// Problem constants
#define B_  16
#define S_  1024
#define D_  512
#define H_  8
#define L_  32
#define DH_ 64

typedef __attribute__((ext_vector_type(8))) short bf16x8;
typedef __attribute__((ext_vector_type(4))) float f32x4;

__device__ __forceinline__ float bf2f(unsigned short u) {
    union { unsigned int u; float f; } x; x.u = ((unsigned int)u) << 16; return x.f;
}
__device__ __forceinline__ unsigned short f2bf(float f) {
    union { float f; unsigned int u; } x; x.f = f;
    unsigned int r = x.u + 0x7fffu + ((x.u >> 16) & 1u);
    return (unsigned short)(r >> 16);
}

// ---------------- prep kernels ----------------

__global__ void k_conv(const float* __restrict__ in, unsigned short* __restrict__ out, int n) {
    int i = (blockIdx.x * 256 + threadIdx.x) * 4;
    int stride = gridDim.x * 1024;
    for (; i < n; i += stride) {
        float4 v = *reinterpret_cast<const float4*>(in + i);
        out[i + 0] = f2bf(v.x); out[i + 1] = f2bf(v.y);
        out[i + 2] = f2bf(v.z); out[i + 3] = f2bf(v.w);
    }
}

// out[c*R + r] = bf16(in[r*C + c]);   block (32,8), grid (C/32, R/32)
__global__ void k_transpose_bf(const float* __restrict__ in, unsigned short* __restrict__ out,
                               int R, int C) {
    __shared__ float tile[32][33];
    int c0 = blockIdx.x * 32, r0 = blockIdx.y * 32;
    int tx = threadIdx.x, ty = threadIdx.y;
#pragma unroll
    for (int i = 0; i < 4; i++)
        tile[ty + i * 8][tx] = in[(size_t)(r0 + ty + i * 8) * C + c0 + tx];
    __syncthreads();
#pragma unroll
    for (int i = 0; i < 4; i++)
        out[(size_t)(c0 + ty + i * 8) * R + r0 + tx] = f2bf(tile[tx][ty + i * 8]);
}

// strip W_ih[:, :512] (row stride 515) into dense bf16 [1536,512]
__global__ void k_conv_wih(const float* __restrict__ in, unsigned short* __restrict__ out) {
    int i = blockIdx.x * 256 + threadIdx.x;   // 786432 total
    int j = i >> 9, k = i & 511;
    out[i] = f2bf(in[j * 515 + k]);
}

// b_f[j] = b_ih[j] + sum_k W_ih[j,k]*bo[k];  Wd[j,c] = W_ih[j,512+c]
__global__ void k_bf_wd(const float* __restrict__ Wih, const float* __restrict__ bih,
                        const float* __restrict__ bo, float* __restrict__ bf_,
                        float* __restrict__ Wd) {
    int j = blockIdx.x * 256 + threadIdx.x;
    if (j >= 1536) return;
    float acc = bih[j];
    for (int k = 0; k < 512; k++) acc += Wih[(size_t)j * 515 + k] * bo[k];
    bf_[j] = acc;
    Wd[j * 3 + 0] = Wih[(size_t)j * 515 + 512];
    Wd[j * 3 + 1] = Wih[(size_t)j * 515 + 513];
    Wd[j * 3 + 2] = Wih[(size_t)j * 515 + 514];
}

// dterm[(l*16+b)*1536 + j] = b_f[j] + sum_c d_in[b,l,c]*Wd[j,c]
__global__ void k_dterm(const float* __restrict__ target, const float* __restrict__ Wd,
                        const float* __restrict__ bf_, float* __restrict__ dterm) {
    int i = blockIdx.x * 256 + threadIdx.x;   // 32*16*1536
    int j = i % 1536; int bl = i / 1536; int b = bl % 16; int l = bl / 16;
    float acc = bf_[j];
    if (l > 0) {
        const float* tg = target + ((size_t)b * L_ + (l - 1)) * 3;
        acc += tg[0] * Wd[j * 3 + 0] + tg[1] * Wd[j * 3 + 1] + tg[2] * Wd[j * 3 + 2];
    }
    dterm[i] = acc;
}

__global__ void k_init_out(float* __restrict__ dout, const float* __restrict__ bout) {
    int i = blockIdx.x * 256 + threadIdx.x;
    if (i < 1536) dout[i] = bout[i % 3];
}

// ---------------- MFMA GEMM: C[M,N] = A[M,K] @ B[N,K]^T (+bias[N]) ----------------
template <bool BF16OUT>
__global__ __launch_bounds__(256) void k_gemm_bt(
    const unsigned short* __restrict__ A, const unsigned short* __restrict__ Bm,
    void* __restrict__ Cout, const float* __restrict__ bias, int M, int N, int Kd) {
    __shared__ unsigned short As[128 * 64];
    __shared__ unsigned short Bs[128 * 64];
    const int t = threadIdx.x;
    const int lane = t & 63;
    const int w = t >> 6, wr = w >> 1, wc = w & 1;
    const int m0 = blockIdx.x * 128, n0 = blockIdx.y * 128;
    f32x4 acc[4][4];
#pragma unroll
    for (int i = 0; i < 4; i++)
#pragma unroll
        for (int j = 0; j < 4; j++) acc[i][j] = (f32x4){0.f, 0.f, 0.f, 0.f};

    const int rowt = t >> 3, colt = (t & 7) * 8;
    for (int k0 = 0; k0 < Kd; k0 += 64) {
#pragma unroll
        for (int i = 0; i < 4; i++) {
            int row = i * 32 + rowt;
            __builtin_amdgcn_global_load_lds(
                (const __attribute__((address_space(1))) unsigned int*)(A + (size_t)(m0 + row) * Kd + k0 + colt),
                (__attribute__((address_space(3))) unsigned int*)(As + (i * 256 + t) * 8), 16, 0, 0);
            __builtin_amdgcn_global_load_lds(
                (const __attribute__((address_space(1))) unsigned int*)(Bm + (size_t)(n0 + row) * Kd + k0 + colt),
                (__attribute__((address_space(3))) unsigned int*)(Bs + (i * 256 + t) * 8), 16, 0, 0);
        }
        asm volatile("s_waitcnt vmcnt(0)" ::: "memory");
        __syncthreads();
#pragma unroll
        for (int kk = 0; kk < 2; kk++) {
            bf16x8 af[4], bfr[4];
#pragma unroll
            for (int mi = 0; mi < 4; mi++)
                af[mi] = *reinterpret_cast<const bf16x8*>(
                    As + (wr * 64 + mi * 16 + (lane & 15)) * 64 + kk * 32 + (lane >> 4) * 8);
#pragma unroll
            for (int ni = 0; ni < 4; ni++)
                bfr[ni] = *reinterpret_cast<const bf16x8*>(
                    Bs + (wc * 64 + ni * 16 + (lane & 15)) * 64 + kk * 32 + (lane >> 4) * 8);
#pragma unroll
            for (int mi = 0; mi < 4; mi++)
#pragma unroll
                for (int ni = 0; ni < 4; ni++)
                    acc[mi][ni] = __builtin_amdgcn_mfma_f32_16x16x32_bf16(af[mi], bfr[ni], acc[mi][ni], 0, 0, 0);
        }
        __syncthreads();
    }
    const int rr = (lane >> 4) * 4, cc = lane & 15;
#pragma unroll
    for (int mi = 0; mi < 4; mi++) {
#pragma unroll
        for (int ni = 0; ni < 4; ni++) {
            int col = n0 + wc * 64 + ni * 16 + cc;
            float bv = bias ? bias[col] : 0.f;
            int rowb = m0 + wr * 64 + mi * 16 + rr;
#pragma unroll
            for (int r = 0; r < 4; r++) {
                float v = acc[mi][ni][r] + bv;
                if (BF16OUT) ((unsigned short*)Cout)[(size_t)(rowb + r) * N + col] = f2bf(v);
                else         ((float*)Cout)[(size_t)(rowb + r) * N + col] = v;
            }
        }
    }
}

// ---- group barrier: 32 blocks of one bi sync via device-scope atomics ----
// Counter is monotone within a launch; zeroed by hipMemsetAsync in the graph, so
// replays are deterministic. Release add + acquire spin + __threadfence for
// cross-XCD visibility (per-XCD L2s are not coherent).
__device__ __forceinline__ void group_barrier(unsigned* bar, unsigned tgt) {
    __threadfence();
    __syncthreads();
    if (threadIdx.x == 0) {
        __hip_atomic_fetch_add(bar, 1u, __ATOMIC_RELEASE, __HIP_MEMORY_SCOPE_AGENT);
        while (__hip_atomic_load(bar, __ATOMIC_ACQUIRE, __HIP_MEMORY_SCOPE_AGENT) < tgt)
            __builtin_amdgcn_s_sleep(2);
    }
    __syncthreads();
    __threadfence();
}

// ---------------- persistent decode kernel: all 32 steps, group barriers ----------------
// grid 512 x 256, 2 blocks/CU guaranteed. Group = 32 blocks sharing bi = bx>>5.
// Phase A: block = (bi,hd,qt) attention chunk. Phase B: block = (bi, dc of 16 d-cols).
__global__ __launch_bounds__(256, 2) void k_decode(
    const unsigned short* __restrict__ K16, const unsigned short* __restrict__ V16,
    const unsigned short* __restrict__ Wq16, const float* __restrict__ bq,
    const unsigned short* __restrict__ Wf16, const unsigned short* __restrict__ Whh16,
    const float* __restrict__ dterm, const float* __restrict__ bhh,
    float* __restrict__ hb0, float* __restrict__ hb1,
    const float* __restrict__ Wout, float* __restrict__ dout,
    float* __restrict__ cross, float* __restrict__ pvP, float* __restrict__ ssumP,
    unsigned* __restrict__ bars) {
    const int t = threadIdx.x, lane = t & 63, w = t >> 6;
    const int bx = blockIdx.x;
    const int bi = bx >> 5;                 // shared by both phases
    const int hd = (bx >> 2) & 7, qt = bx & 3;   // phase A
    const int dc = bx & 31;                 // phase B: d-cols [dc*16, dc*16+16)
    unsigned* bar = bars + bi * 64;         // 256B-spaced counter per group

    __shared__ float hsh[512];
    __shared__ float qsh[64];
    __shared__ float esh[256];
    __shared__ float red[256];
    __shared__ float pvred[256];
    __shared__ float ash[512];
    __shared__ float gsh[96];

    float* hcur = hb0;
    float* hnxt = hb1;
    const size_t base = (size_t)bi * (S_ * D_) + (size_t)hd * (S_ * DH_);

    for (int l = 0; l < L_; l++) {
        // ================= phase A: attention chunk =================
        hsh[t] = hcur[bi * 512 + t];
        hsh[256 + t] = hcur[bi * 512 + 256 + t];
        __syncthreads();

        // q-proj: thread (w,lane) -> col hd*64+lane, k-range [w*128, w*128+128)
        {
            float qa = 0.f;
            const unsigned short* wrow = Wq16 + (size_t)(hd * 64 + lane) * 512 + w * 128;
            const float* xk = hsh + w * 128;
#pragma unroll
            for (int kk = 0; kk < 16; kk++) {
                bf16x8 wv = *reinterpret_cast<const bf16x8*>(wrow + kk * 8);
#pragma unroll
                for (int e = 0; e < 8; e++)
                    qa += xk[kk * 8 + e] * bf2f((unsigned short)wv[e]);
            }
            red[t] = qa;
            __syncthreads();
            if (w == 0)
                qsh[lane] = (red[lane] + red[lane + 64] + red[lane + 128] + red[lane + 192]
                             + bq[hd * 64 + lane]) * (1.f / 32.f);
            __syncthreads();
        }

        // scores; max-free exp (scores are O(0.3) by construction)
        const int s = qt * 256 + t;
        float sc = 0.f;
        {
            const unsigned short* kr = K16 + base + (size_t)s * 64;
#pragma unroll
            for (int c8 = 0; c8 < 8; c8++) {
                bf16x8 kv = *reinterpret_cast<const bf16x8*>(kr + c8 * 8);
#pragma unroll
                for (int e = 0; e < 8; e++)
                    sc += qsh[c8 * 8 + e] * bf2f((unsigned short)kv[e]);
            }
        }
        float e = __expf(sc);
        esh[t] = e;
        cross[((size_t)(bi * 8 + hd) * 32 + l) * 1024 + s] = e;   // unnormalized
        float wsum = e;
#pragma unroll
        for (int off = 1; off < 64; off <<= 1) wsum += __shfl_xor(wsum, off);
        if (lane == 0) red[w] = wsum;
        __syncthreads();
        if (t == 0)
            ssumP[((size_t)(bi * 8 + hd) * 32 + l) * 4 + qt] = red[0] + red[1] + red[2] + red[3];

        // PV partial: wave w covers 64 s-rows; lane -> (d-octet o, s-row srow)
        {
            const int o = lane & 7, srow = lane >> 3;
            float acc[8];
#pragma unroll
            for (int e2 = 0; e2 < 8; e2++) acc[e2] = 0.f;
            const unsigned short* vb = V16 + base + (size_t)(qt * 256 + w * 64 + srow) * 64 + o * 8;
#pragma unroll
            for (int i = 0; i < 8; i++) {
                bf16x8 vv = *reinterpret_cast<const bf16x8*>(vb + (size_t)i * 8 * 64);
                float ev = esh[w * 64 + srow + i * 8];
#pragma unroll
                for (int e2 = 0; e2 < 8; e2++)
                    acc[e2] += ev * bf2f((unsigned short)vv[e2]);
            }
#pragma unroll
            for (int off = 8; off < 64; off <<= 1)
#pragma unroll
                for (int e2 = 0; e2 < 8; e2++)
                    acc[e2] += __shfl_xor(acc[e2], off);
            if (lane < 8) {
#pragma unroll
                for (int e2 = 0; e2 < 8; e2++)
                    pvred[w * 64 + lane * 8 + e2] = acc[e2];
            }
            __syncthreads();
            if (t < 64) {
                float* pv = pvP + ((size_t)((bi * 8 + hd) * 4 + qt)) * 64;
                pv[t] = pvred[t] + pvred[64 + t] + pvred[128 + t] + pvred[192 + t];
            }
        }

        group_barrier(bar, (unsigned)(32 * (2 * l + 1)));

        // ================= phase B: gates for d-cols [dc*16, dc*16+16) =================
        // build ash[512] = normalized attention for bi (hsh still holds h[bi])
        {
            int r0 = t, r1 = t + 256;
            int h20 = r0 >> 6, d20 = r0 & 63;
            const float* sp0 = ssumP + ((size_t)(bi * 8 + h20) * 32 + l) * 4;
            float inv0 = 1.f / (sp0[0] + sp0[1] + sp0[2] + sp0[3]);
            const float* pv0 = pvP + (size_t)((bi * 8 + h20) * 4) * 64 + d20;
            ash[r0] = (pv0[0] + pv0[64] + pv0[128] + pv0[192]) * inv0;
            int h21 = r1 >> 6, d21 = r1 & 63;
            const float* sp1 = ssumP + ((size_t)(bi * 8 + h21) * 32 + l) * 4;
            float inv1 = 1.f / (sp1[0] + sp1[1] + sp1[2] + sp1[3]);
            const float* pv1 = pvP + (size_t)((bi * 8 + h21) * 4) * 64 + d21;
            ash[r1] = (pv1[0] + pv1[64] + pv1[128] + pv1[192]) * inv1;
        }
        __syncthreads();

        // 96 dots (16 d-cols x {gi0,gi1,gi2,gh0,gh1,gh2}), each K-split 2-way
        if (t < 192) {
            const int dotid = t >> 1, p = t & 1;
            const int src = dotid / 48, rem = dotid % 48;
            const int g = rem >> 4, di = rem & 15;
            const int j = g * 512 + dc * 16 + di;
            const unsigned short* wr2 = (src ? Whh16 : Wf16) + (size_t)j * 512 + p * 256;
            const float* x = (src ? hsh : ash) + p * 256;
            float acc = 0.f;
#pragma unroll 8
            for (int kk = 0; kk < 32; kk++) {
                bf16x8 wv = *reinterpret_cast<const bf16x8*>(wr2 + kk * 8);
#pragma unroll
                for (int e2 = 0; e2 < 8; e2++)
                    acc += x[kk * 8 + e2] * bf2f((unsigned short)wv[e2]);
            }
            red[t] = acc;
        }
        __syncthreads();
        if (t < 96) {
            const int src = t / 48, rem = t % 48;
            const int g = rem >> 4, di = rem & 15;
            const int j = g * 512 + dc * 16 + di;
            float tot = red[2 * t] + red[2 * t + 1];
            tot += src ? bhh[j] : dterm[((size_t)l * 16 + bi) * 1536 + j];
            gsh[t] = tot;   // layout: src*48 + g*16 + di == t
        }
        __syncthreads();
        if (t < 16) {
            const int d = dc * 16 + t;
            float gi0 = gsh[t], gi1 = gsh[16 + t], gi2 = gsh[32 + t];
            float gh0 = gsh[48 + t], gh1 = gsh[64 + t], gh2 = gsh[80 + t];
            float r = 1.f / (1.f + __expf(-(gi0 + gh0)));
            float z = 1.f / (1.f + __expf(-(gi1 + gh1)));
            float n = tanhf(gi2 + r * gh2);
            float hnew = (1.f - z) * n + z * hsh[d];
            hnxt[bi * 512 + d] = hnew;
            red[t]      = hnew * Wout[d];
            red[16 + t] = hnew * Wout[512 + d];
            red[32 + t] = hnew * Wout[1024 + d];
        }
        __syncthreads();
        if (t < 3) {
            float sacc = 0.f;
#pragma unroll
            for (int i2 = 0; i2 < 16; i2++) sacc += red[t * 16 + i2];
            atomicAdd(dout + ((size_t)bi * 32 + l) * 3 + t, sacc);
        }

        group_barrier(bar, (unsigned)(32 * (2 * l + 2)));

        float* tmp = hcur; hcur = hnxt; hnxt = tmp;
    }
}

// ---------------- deferred cross normalization: cross[b,h,l,s] /= sum ----------------
// grid 4096 x 256: full cross [16,8,32,1024]
__global__ void k_norm(float* __restrict__ cross, const float* __restrict__ ssumP) {
    int i = blockIdx.x * 256 + threadIdx.x;
    size_t b4 = (size_t)i * 4;
    int bhl = (int)(b4 >> 10);
    const float* sp = ssumP + (size_t)bhl * 4;
    float inv = 1.f / (sp[0] + sp[1] + sp[2] + sp[3]);
    float4 v = *reinterpret_cast<float4*>(cross + b4);
    v.x *= inv; v.y *= inv; v.z *= inv; v.w *= inv;
    *reinterpret_cast<float4*>(cross + b4) = v;
}

// ---------------- launch ----------------
extern "C" void kernel_launch(void* const* d_in, const int* in_sizes, int n_in,
                              void* d_out, int out_size, void* d_ws, size_t ws_size,
                              hipStream_t stream) {
    (void)in_sizes; (void)n_in; (void)out_size; (void)ws_size;
    const float* e_all  = (const float*)d_in[0];
    const float* e_last = (const float*)d_in[1];
    const float* target = (const float*)d_in[2];
    const float* Wq     = (const float*)d_in[3];
    const float* bq     = (const float*)d_in[4];
    const float* Wk     = (const float*)d_in[5];
    const float* bk     = (const float*)d_in[6];
    const float* Wv     = (const float*)d_in[7];
    const float* bv     = (const float*)d_in[8];
    const float* Wo     = (const float*)d_in[9];
    const float* bo     = (const float*)d_in[10];
    const float* W_ih   = (const float*)d_in[11];
    const float* W_hh   = (const float*)d_in[12];
    const float* b_ih   = (const float*)d_in[13];
    const float* b_hh   = (const float*)d_in[14];
    const float* W_out  = (const float*)d_in[15];
    const float* b_out  = (const float*)d_in[16];
    float* out = (float*)d_out;

    char* ws = (char*)d_ws;
    size_t off = 0;
    auto alloc = [&](size_t bytes) -> void* {
        void* p = ws + off; off += (bytes + 255) & ~(size_t)255; return p;
    };
    unsigned short* eA    = (unsigned short*)alloc(16777216);
    unsigned short* K16   = (unsigned short*)alloc(16777216);
    unsigned short* V16   = (unsigned short*)alloc(16777216);
    unsigned short* Wk16  = (unsigned short*)alloc(524288);
    unsigned short* Wv16  = (unsigned short*)alloc(524288);
    unsigned short* Wq16  = (unsigned short*)alloc(524288);
    unsigned short* Whh16 = (unsigned short*)alloc(1572864);
    unsigned short* Wih16 = (unsigned short*)alloc(1572864);
    unsigned short* WoT   = (unsigned short*)alloc(524288);
    unsigned short* Wf16  = (unsigned short*)alloc(1572864);
    float* Wf32  = (float*)alloc(3145728);
    float* bf_   = (float*)alloc(6144);
    float* Wd    = (float*)alloc(18432);
    float* dterm = (float*)alloc(3145728);
    float* hb0   = (float*)alloc(32768);
    float* hb1   = (float*)alloc(32768);
    float* pvP   = (float*)alloc(131072);   // [16][8][4][64] f32
    float* ssumP = (float*)alloc(65536);    // [16][8][32][4] f32
    unsigned* bars = (unsigned*)alloc(4096); // 16 groups x 256B

    float* d_outputs = out;          // [16,32,3]
    float* h_fin     = out + 1536;   // [1,16,512]
    float* cross     = out + 9728;   // [16,8,32,1024]

    // one-time prep
    hipMemsetAsync(bars, 0, 4096, stream);
    k_conv<<<2048, 256, 0, stream>>>(e_all, eA, 8388608);
    k_conv<<<256, 256, 0, stream>>>(Wk, Wk16, 262144);
    k_conv<<<256, 256, 0, stream>>>(Wv, Wv16, 262144);
    k_conv<<<256, 256, 0, stream>>>(Wq, Wq16, 262144);
    k_conv<<<768, 256, 0, stream>>>(W_hh, Whh16, 786432);
    k_transpose_bf<<<dim3(16, 16), dim3(32, 8), 0, stream>>>(Wo, WoT, 512, 512);
    k_conv_wih<<<3072, 256, 0, stream>>>(W_ih, Wih16);
    k_bf_wd<<<6, 256, 0, stream>>>(W_ih, b_ih, bo, bf_, Wd);
    k_dterm<<<3072, 256, 0, stream>>>(target, Wd, bf_, dterm);
    k_gemm_bt<true><<<dim3(128, 4), 256, 0, stream>>>(eA, Wk16, K16, bk, 16384, 512, 512);
    k_gemm_bt<true><<<dim3(128, 4), 256, 0, stream>>>(eA, Wv16, V16, bv, 16384, 512, 512);
    k_gemm_bt<false><<<dim3(12, 4), 256, 0, stream>>>(Wih16, WoT, Wf32, nullptr, 1536, 512, 512);
    k_conv<<<768, 256, 0, stream>>>(Wf32, Wf16, 786432);
    k_init_out<<<6, 256, 0, stream>>>(d_outputs, b_out);
    hipMemcpyAsync(hb0, e_last, 8192 * sizeof(float), hipMemcpyDeviceToDevice, stream);

    // persistent decode: all 32 steps in one plain launch, group barriers inside
    k_decode<<<512, 256, 0, stream>>>(K16, V16, Wq16, bq, Wf16, Whh16, dterm, b_hh,
                                      hb0, hb1, W_out, d_outputs, cross, pvP, ssumP, bars);

    k_norm<<<4096, 256, 0, stream>>>(cross, ssumP);
    hipMemcpyAsync(h_fin, hb0, 8192 * sizeof(float), hipMemcpyDeviceToDevice, stream);
}

// Round 7
// 1393.228 us; speedup vs baseline: 4.6968x; 4.6968x over previous
//
#include <hip/hip_runtime.h>
#include <hip/hip_bf16.h>
#include <cstdint>

// Problem constants
#define B_  16
#define S_  1024
#define D_  512
#define H_  8
#define L_  32
#define DH_ 64

typedef __attribute__((ext_vector_type(8))) short bf16x8;
typedef __attribute__((ext_vector_type(4))) float f32x4;

__device__ __forceinline__ float bf2f(unsigned short u) {
    union { unsigned int u; float f; } x; x.u = ((unsigned int)u) << 16; return x.f;
}
__device__ __forceinline__ unsigned short f2bf(float f) {
    union { float f; unsigned int u; } x; x.f = f;
    unsigned int r = x.u + 0x7fffu + ((x.u >> 16) & 1u);
    return (unsigned short)(r >> 16);
}

// agent-scope (device) coherent access helpers: compile to cache-bypassing
// loads/stores that hit the coherent point (LLC) -- no L1/L2 flush needed.
__device__ __forceinline__ void st_dev(float* p, float v) {
    __hip_atomic_store(p, v, __ATOMIC_RELAXED, __HIP_MEMORY_SCOPE_AGENT);
}
__device__ __forceinline__ float ld_dev(const float* p) {
    return __hip_atomic_load(p, __ATOMIC_RELAXED, __HIP_MEMORY_SCOPE_AGENT);
}

// ---------------- prep kernels ----------------

__global__ void k_conv(const float* __restrict__ in, unsigned short* __restrict__ out, int n) {
    int i = (blockIdx.x * 256 + threadIdx.x) * 4;
    int stride = gridDim.x * 1024;
    for (; i < n; i += stride) {
        float4 v = *reinterpret_cast<const float4*>(in + i);
        out[i + 0] = f2bf(v.x); out[i + 1] = f2bf(v.y);
        out[i + 2] = f2bf(v.z); out[i + 3] = f2bf(v.w);
    }
}

// out[c*R + r] = bf16(in[r*C + c]);   block (32,8), grid (C/32, R/32)
__global__ void k_transpose_bf(const float* __restrict__ in, unsigned short* __restrict__ out,
                               int R, int C) {
    __shared__ float tile[32][33];
    int c0 = blockIdx.x * 32, r0 = blockIdx.y * 32;
    int tx = threadIdx.x, ty = threadIdx.y;
#pragma unroll
    for (int i = 0; i < 4; i++)
        tile[ty + i * 8][tx] = in[(size_t)(r0 + ty + i * 8) * C + c0 + tx];
    __syncthreads();
#pragma unroll
    for (int i = 0; i < 4; i++)
        out[(size_t)(c0 + ty + i * 8) * R + r0 + tx] = f2bf(tile[tx][ty + i * 8]);
}

// strip W_ih[:, :512] (row stride 515) into dense bf16 [1536,512]
__global__ void k_conv_wih(const float* __restrict__ in, unsigned short* __restrict__ out) {
    int i = blockIdx.x * 256 + threadIdx.x;   // 786432 total
    int j = i >> 9, k = i & 511;
    out[i] = f2bf(in[j * 515 + k]);
}

// b_f[j] = b_ih[j] + sum_k W_ih[j,k]*bo[k];  Wd[j,c] = W_ih[j,512+c]
__global__ void k_bf_wd(const float* __restrict__ Wih, const float* __restrict__ bih,
                        const float* __restrict__ bo, float* __restrict__ bf_,
                        float* __restrict__ Wd) {
    int j = blockIdx.x * 256 + threadIdx.x;
    if (j >= 1536) return;
    float acc = bih[j];
    for (int k = 0; k < 512; k++) acc += Wih[(size_t)j * 515 + k] * bo[k];
    bf_[j] = acc;
    Wd[j * 3 + 0] = Wih[(size_t)j * 515 + 512];
    Wd[j * 3 + 1] = Wih[(size_t)j * 515 + 513];
    Wd[j * 3 + 2] = Wih[(size_t)j * 515 + 514];
}

// dterm[(l*16+b)*1536 + j] = b_f[j] + sum_c d_in[b,l,c]*Wd[j,c]
__global__ void k_dterm(const float* __restrict__ target, const float* __restrict__ Wd,
                        const float* __restrict__ bf_, float* __restrict__ dterm) {
    int i = blockIdx.x * 256 + threadIdx.x;   // 32*16*1536
    int j = i % 1536; int bl = i / 1536; int b = bl % 16; int l = bl / 16;
    float acc = bf_[j];
    if (l > 0) {
        const float* tg = target + ((size_t)b * L_ + (l - 1)) * 3;
        acc += tg[0] * Wd[j * 3 + 0] + tg[1] * Wd[j * 3 + 1] + tg[2] * Wd[j * 3 + 2];
    }
    dterm[i] = acc;
}

__global__ void k_init_out(float* __restrict__ dout, const float* __restrict__ bout) {
    int i = blockIdx.x * 256 + threadIdx.x;
    if (i < 1536) dout[i] = bout[i % 3];
}

// ---------------- MFMA GEMM: C[M,N] = A[M,K] @ B[N,K]^T (+bias[N]) ----------------
template <bool BF16OUT>
__global__ __launch_bounds__(256) void k_gemm_bt(
    const unsigned short* __restrict__ A, const unsigned short* __restrict__ Bm,
    void* __restrict__ Cout, const float* __restrict__ bias, int M, int N, int Kd) {
    __shared__ unsigned short As[128 * 64];
    __shared__ unsigned short Bs[128 * 64];
    const int t = threadIdx.x;
    const int lane = t & 63;
    const int w = t >> 6, wr = w >> 1, wc = w & 1;
    const int m0 = blockIdx.x * 128, n0 = blockIdx.y * 128;
    f32x4 acc[4][4];
#pragma unroll
    for (int i = 0; i < 4; i++)
#pragma unroll
        for (int j = 0; j < 4; j++) acc[i][j] = (f32x4){0.f, 0.f, 0.f, 0.f};

    const int rowt = t >> 3, colt = (t & 7) * 8;
    for (int k0 = 0; k0 < Kd; k0 += 64) {
#pragma unroll
        for (int i = 0; i < 4; i++) {
            int row = i * 32 + rowt;
            __builtin_amdgcn_global_load_lds(
                (const __attribute__((address_space(1))) unsigned int*)(A + (size_t)(m0 + row) * Kd + k0 + colt),
                (__attribute__((address_space(3))) unsigned int*)(As + (i * 256 + t) * 8), 16, 0, 0);
            __builtin_amdgcn_global_load_lds(
                (const __attribute__((address_space(1))) unsigned int*)(Bm + (size_t)(n0 + row) * Kd + k0 + colt),
                (__attribute__((address_space(3))) unsigned int*)(Bs + (i * 256 + t) * 8), 16, 0, 0);
        }
        asm volatile("s_waitcnt vmcnt(0)" ::: "memory");
        __syncthreads();
#pragma unroll
        for (int kk = 0; kk < 2; kk++) {
            bf16x8 af[4], bfr[4];
#pragma unroll
            for (int mi = 0; mi < 4; mi++)
                af[mi] = *reinterpret_cast<const bf16x8*>(
                    As + (wr * 64 + mi * 16 + (lane & 15)) * 64 + kk * 32 + (lane >> 4) * 8);
#pragma unroll
            for (int ni = 0; ni < 4; ni++)
                bfr[ni] = *reinterpret_cast<const bf16x8*>(
                    Bs + (wc * 64 + ni * 16 + (lane & 15)) * 64 + kk * 32 + (lane >> 4) * 8);
#pragma unroll
            for (int mi = 0; mi < 4; mi++)
#pragma unroll
                for (int ni = 0; ni < 4; ni++)
                    acc[mi][ni] = __builtin_amdgcn_mfma_f32_16x16x32_bf16(af[mi], bfr[ni], acc[mi][ni], 0, 0, 0);
        }
        __syncthreads();
    }
    const int rr = (lane >> 4) * 4, cc = lane & 15;
#pragma unroll
    for (int mi = 0; mi < 4; mi++) {
#pragma unroll
        for (int ni = 0; ni < 4; ni++) {
            int col = n0 + wc * 64 + ni * 16 + cc;
            float bv = bias ? bias[col] : 0.f;
            int rowb = m0 + wr * 64 + mi * 16 + rr;
#pragma unroll
            for (int r = 0; r < 4; r++) {
                float v = acc[mi][ni][r] + bv;
                if (BF16OUT) ((unsigned short*)Cout)[(size_t)(rowb + r) * N + col] = f2bf(v);
                else         ((float*)Cout)[(size_t)(rowb + r) * N + col] = v;
            }
        }
    }
}

// ---- group barrier: 32 blocks of one bi, one counter per barrier instance ----
// No __threadfence (that flushed L1/L2 and killed K/V reuse -- round 6 lesson).
// Writer ordering: s_waitcnt vmcnt(0) drains prior cache-bypassing (agent-scope)
// stores to the LLC, then the counter bump. Reader: spin on cache-bypassing load,
// then __syncthreads; data reads are themselves agent-scope (LLC) loads.
__device__ __forceinline__ void group_barrier(unsigned* bar) {
    __syncthreads();
    if (threadIdx.x == 0) {
        asm volatile("s_waitcnt vmcnt(0)" ::: "memory");
        __hip_atomic_fetch_add(bar, 1u, __ATOMIC_RELAXED, __HIP_MEMORY_SCOPE_AGENT);
        while (__hip_atomic_load(bar, __ATOMIC_RELAXED, __HIP_MEMORY_SCOPE_AGENT) < 32u)
            __builtin_amdgcn_s_sleep(1);
    }
    __syncthreads();
}

// ---------------- persistent decode kernel: all 32 steps, group barriers ----------------
// grid 512 x 256, 2 blocks/CU co-resident. Group = 32 blocks sharing bi = bx>>5.
// Phase A: block = (bi,hd,qt) attention chunk. Phase B: block = (bi, dc of 16 d-cols).
// Cross-block data (pvP/ssumP/h) via agent-scope ld/st; K/V/weights stay cached.
__global__ __launch_bounds__(256, 2) void k_decode(
    const unsigned short* __restrict__ K16, const unsigned short* __restrict__ V16,
    const unsigned short* __restrict__ Wq16, const float* __restrict__ bq,
    const unsigned short* __restrict__ Wf16, const unsigned short* __restrict__ Whh16,
    const float* __restrict__ dterm, const float* __restrict__ bhh,
    float* __restrict__ hb0, float* __restrict__ hb1,
    const float* __restrict__ Wout, float* __restrict__ dout,
    float* __restrict__ cross, float* __restrict__ pvP, float* __restrict__ ssumP,
    unsigned* __restrict__ bars) {
    const int t = threadIdx.x, lane = t & 63, w = t >> 6;
    const int bx = blockIdx.x;
    const int bi = bx >> 5;                 // shared by both phases
    const int hd = (bx >> 2) & 7, qt = bx & 3;   // phase A
    const int dc = bx & 31;                 // phase B: d-cols [dc*16, dc*16+16)
    unsigned* barbase = bars + bi * 64;     // 64 counters (one per barrier instance)

    __shared__ float hsh[512];
    __shared__ float qsh[64];
    __shared__ float esh[256];
    __shared__ float red[256];
    __shared__ float pvred[256];
    __shared__ float ash[512];
    __shared__ float gsh[96];

    float* hcur = hb0;
    float* hnxt = hb1;
    const size_t base = (size_t)bi * (S_ * D_) + (size_t)hd * (S_ * DH_);

    for (int l = 0; l < L_; l++) {
        // ================= phase A: attention chunk =================
        hsh[t] = ld_dev(hcur + bi * 512 + t);
        hsh[256 + t] = ld_dev(hcur + bi * 512 + 256 + t);
        __syncthreads();

        // q-proj: thread (w,lane) -> col hd*64+lane, k-range [w*128, w*128+128)
        {
            float qa = 0.f;
            const unsigned short* wrow = Wq16 + (size_t)(hd * 64 + lane) * 512 + w * 128;
            const float* xk = hsh + w * 128;
#pragma unroll
            for (int kk = 0; kk < 16; kk++) {
                bf16x8 wv = *reinterpret_cast<const bf16x8*>(wrow + kk * 8);
#pragma unroll
                for (int e = 0; e < 8; e++)
                    qa += xk[kk * 8 + e] * bf2f((unsigned short)wv[e]);
            }
            red[t] = qa;
            __syncthreads();
            if (w == 0)
                qsh[lane] = (red[lane] + red[lane + 64] + red[lane + 128] + red[lane + 192]
                             + bq[hd * 64 + lane]) * (1.f / 32.f);
            __syncthreads();
        }

        // scores; max-free exp (scores are O(0.3) by construction)
        const int s = qt * 256 + t;
        float sc = 0.f;
        {
            const unsigned short* kr = K16 + base + (size_t)s * 64;
#pragma unroll
            for (int c8 = 0; c8 < 8; c8++) {
                bf16x8 kv = *reinterpret_cast<const bf16x8*>(kr + c8 * 8);
#pragma unroll
                for (int e = 0; e < 8; e++)
                    sc += qsh[c8 * 8 + e] * bf2f((unsigned short)kv[e]);
            }
        }
        float e = __expf(sc);
        esh[t] = e;
        cross[((size_t)(bi * 8 + hd) * 32 + l) * 1024 + s] = e;   // read only after kernel end
        float wsum = e;
#pragma unroll
        for (int off = 1; off < 64; off <<= 1) wsum += __shfl_xor(wsum, off);
        if (lane == 0) red[w] = wsum;
        __syncthreads();
        if (t == 0)
            st_dev(ssumP + ((size_t)(bi * 8 + hd) * 32 + l) * 4 + qt,
                   red[0] + red[1] + red[2] + red[3]);

        // PV partial: wave w covers 64 s-rows; lane -> (d-octet o, s-row srow)
        {
            const int o = lane & 7, srow = lane >> 3;
            float acc[8];
#pragma unroll
            for (int e2 = 0; e2 < 8; e2++) acc[e2] = 0.f;
            const unsigned short* vb = V16 + base + (size_t)(qt * 256 + w * 64 + srow) * 64 + o * 8;
#pragma unroll
            for (int i = 0; i < 8; i++) {
                bf16x8 vv = *reinterpret_cast<const bf16x8*>(vb + (size_t)i * 8 * 64);
                float ev = esh[w * 64 + srow + i * 8];
#pragma unroll
                for (int e2 = 0; e2 < 8; e2++)
                    acc[e2] += ev * bf2f((unsigned short)vv[e2]);
            }
#pragma unroll
            for (int off = 8; off < 64; off <<= 1)
#pragma unroll
                for (int e2 = 0; e2 < 8; e2++)
                    acc[e2] += __shfl_xor(acc[e2], off);
            if (lane < 8) {
#pragma unroll
                for (int e2 = 0; e2 < 8; e2++)
                    pvred[w * 64 + lane * 8 + e2] = acc[e2];
            }
            __syncthreads();
            if (t < 64) {
                float* pv = pvP + ((size_t)((bi * 8 + hd) * 4 + qt)) * 64;
                st_dev(pv + t, pvred[t] + pvred[64 + t] + pvred[128 + t] + pvred[192 + t]);
            }
        }

        group_barrier(barbase + 2 * l);

        // ================= phase B: gates for d-cols [dc*16, dc*16+16) =================
        // build ash[512] = normalized attention for bi (hsh still holds h[bi])
        {
            int r0 = t, r1 = t + 256;
            int h20 = r0 >> 6, d20 = r0 & 63;
            const float* sp0 = ssumP + ((size_t)(bi * 8 + h20) * 32 + l) * 4;
            float inv0 = 1.f / (ld_dev(sp0 + 0) + ld_dev(sp0 + 1) + ld_dev(sp0 + 2) + ld_dev(sp0 + 3));
            const float* pv0 = pvP + (size_t)((bi * 8 + h20) * 4) * 64 + d20;
            ash[r0] = (ld_dev(pv0 + 0) + ld_dev(pv0 + 64) + ld_dev(pv0 + 128) + ld_dev(pv0 + 192)) * inv0;
            int h21 = r1 >> 6, d21 = r1 & 63;
            const float* sp1 = ssumP + ((size_t)(bi * 8 + h21) * 32 + l) * 4;
            float inv1 = 1.f / (ld_dev(sp1 + 0) + ld_dev(sp1 + 1) + ld_dev(sp1 + 2) + ld_dev(sp1 + 3));
            const float* pv1 = pvP + (size_t)((bi * 8 + h21) * 4) * 64 + d21;
            ash[r1] = (ld_dev(pv1 + 0) + ld_dev(pv1 + 64) + ld_dev(pv1 + 128) + ld_dev(pv1 + 192)) * inv1;
        }
        __syncthreads();

        // 96 dots (16 d-cols x {gi0,gi1,gi2,gh0,gh1,gh2}), each K-split 2-way
        if (t < 192) {
            const int dotid = t >> 1, p = t & 1;
            const int src = dotid / 48, rem = dotid % 48;
            const int g = rem >> 4, di = rem & 15;
            const int j = g * 512 + dc * 16 + di;
            const unsigned short* wr2 = (src ? Whh16 : Wf16) + (size_t)j * 512 + p * 256;
            const float* x = (src ? hsh : ash) + p * 256;
            float acc = 0.f;
#pragma unroll 8
            for (int kk = 0; kk < 32; kk++) {
                bf16x8 wv = *reinterpret_cast<const bf16x8*>(wr2 + kk * 8);
#pragma unroll
                for (int e2 = 0; e2 < 8; e2++)
                    acc += x[kk * 8 + e2] * bf2f((unsigned short)wv[e2]);
            }
            red[t] = acc;
        }
        __syncthreads();
        if (t < 96) {
            const int src = t / 48, rem = t % 48;
            const int g = rem >> 4, di = rem & 15;
            const int j = g * 512 + dc * 16 + di;
            float tot = red[2 * t] + red[2 * t + 1];
            tot += src ? bhh[j] : dterm[((size_t)l * 16 + bi) * 1536 + j];
            gsh[t] = tot;   // layout: src*48 + g*16 + di == t
        }
        __syncthreads();
        if (t < 16) {
            const int d = dc * 16 + t;
            float gi0 = gsh[t], gi1 = gsh[16 + t], gi2 = gsh[32 + t];
            float gh0 = gsh[48 + t], gh1 = gsh[64 + t], gh2 = gsh[80 + t];
            float r = 1.f / (1.f + __expf(-(gi0 + gh0)));
            float z = 1.f / (1.f + __expf(-(gi1 + gh1)));
            float n = tanhf(gi2 + r * gh2);
            float hnew = (1.f - z) * n + z * hsh[d];
            st_dev(hnxt + bi * 512 + d, hnew);
            red[t]      = hnew * Wout[d];
            red[16 + t] = hnew * Wout[512 + d];
            red[32 + t] = hnew * Wout[1024 + d];
        }
        __syncthreads();
        if (t < 3) {
            float sacc = 0.f;
#pragma unroll
            for (int i2 = 0; i2 < 16; i2++) sacc += red[t * 16 + i2];
            atomicAdd(dout + ((size_t)bi * 32 + l) * 3 + t, sacc);
        }

        group_barrier(barbase + 2 * l + 1);

        float* tmp = hcur; hcur = hnxt; hnxt = tmp;
    }
}

// ---------------- deferred cross normalization: cross[b,h,l,s] /= sum ----------------
// grid 4096 x 256: full cross [16,8,32,1024]
__global__ void k_norm(float* __restrict__ cross, const float* __restrict__ ssumP) {
    int i = blockIdx.x * 256 + threadIdx.x;
    size_t b4 = (size_t)i * 4;
    int bhl = (int)(b4 >> 10);
    const float* sp = ssumP + (size_t)bhl * 4;
    float inv = 1.f / (sp[0] + sp[1] + sp[2] + sp[3]);
    float4 v = *reinterpret_cast<float4*>(cross + b4);
    v.x *= inv; v.y *= inv; v.z *= inv; v.w *= inv;
    *reinterpret_cast<float4*>(cross + b4) = v;
}

// ---------------- launch ----------------
extern "C" void kernel_launch(void* const* d_in, const int* in_sizes, int n_in,
                              void* d_out, int out_size, void* d_ws, size_t ws_size,
                              hipStream_t stream) {
    (void)in_sizes; (void)n_in; (void)out_size; (void)ws_size;
    const float* e_all  = (const float*)d_in[0];
    const float* e_last = (const float*)d_in[1];
    const float* target = (const float*)d_in[2];
    const float* Wq     = (const float*)d_in[3];
    const float* bq     = (const float*)d_in[4];
    const float* Wk     = (const float*)d_in[5];
    const float* bk     = (const float*)d_in[6];
    const float* Wv     = (const float*)d_in[7];
    const float* bv     = (const float*)d_in[8];
    const float* Wo     = (const float*)d_in[9];
    const float* bo     = (const float*)d_in[10];
    const float* W_ih   = (const float*)d_in[11];
    const float* W_hh   = (const float*)d_in[12];
    const float* b_ih   = (const float*)d_in[13];
    const float* b_hh   = (const float*)d_in[14];
    const float* W_out  = (const float*)d_in[15];
    const float* b_out  = (const float*)d_in[16];
    float* out = (float*)d_out;

    char* ws = (char*)d_ws;
    size_t off = 0;
    auto alloc = [&](size_t bytes) -> void* {
        void* p = ws + off; off += (bytes + 255) & ~(size_t)255; return p;
    };
    unsigned short* eA    = (unsigned short*)alloc(16777216);
    unsigned short* K16   = (unsigned short*)alloc(16777216);
    unsigned short* V16   = (unsigned short*)alloc(16777216);
    unsigned short* Wk16  = (unsigned short*)alloc(524288);
    unsigned short* Wv16  = (unsigned short*)alloc(524288);
    unsigned short* Wq16  = (unsigned short*)alloc(524288);
    unsigned short* Whh16 = (unsigned short*)alloc(1572864);
    unsigned short* Wih16 = (unsigned short*)alloc(1572864);
    unsigned short* WoT   = (unsigned short*)alloc(524288);
    unsigned short* Wf16  = (unsigned short*)alloc(1572864);
    float* Wf32  = (float*)alloc(3145728);
    float* bf_   = (float*)alloc(6144);
    float* Wd    = (float*)alloc(18432);
    float* dterm = (float*)alloc(3145728);
    float* hb0   = (float*)alloc(32768);
    float* hb1   = (float*)alloc(32768);
    float* pvP   = (float*)alloc(131072);   // [16][8][4][64] f32
    float* ssumP = (float*)alloc(65536);    // [16][8][32][4] f32
    unsigned* bars = (unsigned*)alloc(4096); // 16 groups x 64 barrier instances

    float* d_outputs = out;          // [16,32,3]
    float* h_fin     = out + 1536;   // [1,16,512]
    float* cross     = out + 9728;   // [16,8,32,1024]

    // one-time prep
    hipMemsetAsync(bars, 0, 4096, stream);
    k_conv<<<2048, 256, 0, stream>>>(e_all, eA, 8388608);
    k_conv<<<256, 256, 0, stream>>>(Wk, Wk16, 262144);
    k_conv<<<256, 256, 0, stream>>>(Wv, Wv16, 262144);
    k_conv<<<256, 256, 0, stream>>>(Wq, Wq16, 262144);
    k_conv<<<768, 256, 0, stream>>>(W_hh, Whh16, 786432);
    k_transpose_bf<<<dim3(16, 16), dim3(32, 8), 0, stream>>>(Wo, WoT, 512, 512);
    k_conv_wih<<<3072, 256, 0, stream>>>(W_ih, Wih16);
    k_bf_wd<<<6, 256, 0, stream>>>(W_ih, b_ih, bo, bf_, Wd);
    k_dterm<<<3072, 256, 0, stream>>>(target, Wd, bf_, dterm);
    k_gemm_bt<true><<<dim3(128, 4), 256, 0, stream>>>(eA, Wk16, K16, bk, 16384, 512, 512);
    k_gemm_bt<true><<<dim3(128, 4), 256, 0, stream>>>(eA, Wv16, V16, bv, 16384, 512, 512);
    k_gemm_bt<false><<<dim3(12, 4), 256, 0, stream>>>(Wih16, WoT, Wf32, nullptr, 1536, 512, 512);
    k_conv<<<768, 256, 0, stream>>>(Wf32, Wf16, 786432);
    k_init_out<<<6, 256, 0, stream>>>(d_outputs, b_out);
    hipMemcpyAsync(hb0, e_last, 8192 * sizeof(float), hipMemcpyDeviceToDevice, stream);

    // persistent decode: all 32 steps in one plain launch, cheap group barriers inside
    k_decode<<<512, 256, 0, stream>>>(K16, V16, Wq16, bq, Wf16, Whh16, dterm, b_hh,
                                      hb0, hb1, W_out, d_outputs, cross, pvP, ssumP, bars);

    k_norm<<<4096, 256, 0, stream>>>(cross, ssumP);
    hipMemcpyAsync(h_fin, hb0, 8192 * sizeof(float), hipMemcpyDeviceToDevice, stream);
}

// Round 8
// 1006.733 us; speedup vs baseline: 6.4999x; 1.3839x over previous
//
#include <hip/hip_runtime.h>
#include <hip/hip_bf16.h>
#include <cstdint>

// Problem constants
#define B_  16
#define S_  1024
#define D_  512
#define H_  8
#define L_  32
#define DH_ 64

typedef __attribute__((ext_vector_type(8))) short bf16x8;
typedef __attribute__((ext_vector_type(4))) float f32x4;

__device__ __forceinline__ float bf2f(unsigned short u) {
    union { unsigned int u; float f; } x; x.u = ((unsigned int)u) << 16; return x.f;
}
__device__ __forceinline__ unsigned short f2bf(float f) {
    union { float f; unsigned int u; } x; x.f = f;
    unsigned int r = x.u + 0x7fffu + ((x.u >> 16) & 1u);
    return (unsigned short)(r >> 16);
}

// agent-scope (device) coherent access helpers: cache-bypassing, hit the LLC.
__device__ __forceinline__ void st_dev(float* p, float v) {
    __hip_atomic_store(p, v, __ATOMIC_RELAXED, __HIP_MEMORY_SCOPE_AGENT);
}
__device__ __forceinline__ float ld_dev(const float* p) {
    return __hip_atomic_load(p, __ATOMIC_RELAXED, __HIP_MEMORY_SCOPE_AGENT);
}

// ---------------- prep kernels ----------------

__global__ void k_conv(const float* __restrict__ in, unsigned short* __restrict__ out, int n) {
    int i = (blockIdx.x * 256 + threadIdx.x) * 4;
    int stride = gridDim.x * 1024;
    for (; i < n; i += stride) {
        float4 v = *reinterpret_cast<const float4*>(in + i);
        out[i + 0] = f2bf(v.x); out[i + 1] = f2bf(v.y);
        out[i + 2] = f2bf(v.z); out[i + 3] = f2bf(v.w);
    }
}

// out[c*R + r] = bf16(in[r*C + c]);   block (32,8), grid (C/32, R/32)
__global__ void k_transpose_bf(const float* __restrict__ in, unsigned short* __restrict__ out,
                               int R, int C) {
    __shared__ float tile[32][33];
    int c0 = blockIdx.x * 32, r0 = blockIdx.y * 32;
    int tx = threadIdx.x, ty = threadIdx.y;
#pragma unroll
    for (int i = 0; i < 4; i++)
        tile[ty + i * 8][tx] = in[(size_t)(r0 + ty + i * 8) * C + c0 + tx];
    __syncthreads();
#pragma unroll
    for (int i = 0; i < 4; i++)
        out[(size_t)(c0 + ty + i * 8) * R + r0 + tx] = f2bf(tile[tx][ty + i * 8]);
}

// strip W_ih[:, :512] (row stride 515) into dense bf16 [1536,512]
__global__ void k_conv_wih(const float* __restrict__ in, unsigned short* __restrict__ out) {
    int i = blockIdx.x * 256 + threadIdx.x;   // 786432 total
    int j = i >> 9, k = i & 511;
    out[i] = f2bf(in[j * 515 + k]);
}

// b_f[j] = b_ih[j] + sum_k W_ih[j,k]*bo[k];  Wd[j,c] = W_ih[j,512+c]
__global__ void k_bf_wd(const float* __restrict__ Wih, const float* __restrict__ bih,
                        const float* __restrict__ bo, float* __restrict__ bf_,
                        float* __restrict__ Wd) {
    int j = blockIdx.x * 256 + threadIdx.x;
    if (j >= 1536) return;
    float acc = bih[j];
    for (int k = 0; k < 512; k++) acc += Wih[(size_t)j * 515 + k] * bo[k];
    bf_[j] = acc;
    Wd[j * 3 + 0] = Wih[(size_t)j * 515 + 512];
    Wd[j * 3 + 1] = Wih[(size_t)j * 515 + 513];
    Wd[j * 3 + 2] = Wih[(size_t)j * 515 + 514];
}

// dterm[(l*16+b)*1536 + j] = b_f[j] + sum_c d_in[b,l,c]*Wd[j,c]
__global__ void k_dterm(const float* __restrict__ target, const float* __restrict__ Wd,
                        const float* __restrict__ bf_, float* __restrict__ dterm) {
    int i = blockIdx.x * 256 + threadIdx.x;   // 32*16*1536
    int j = i % 1536; int bl = i / 1536; int b = bl % 16; int l = bl / 16;
    float acc = bf_[j];
    if (l > 0) {
        const float* tg = target + ((size_t)b * L_ + (l - 1)) * 3;
        acc += tg[0] * Wd[j * 3 + 0] + tg[1] * Wd[j * 3 + 1] + tg[2] * Wd[j * 3 + 2];
    }
    dterm[i] = acc;
}

__global__ void k_init_out(float* __restrict__ dout, const float* __restrict__ bout) {
    int i = blockIdx.x * 256 + threadIdx.x;
    if (i < 1536) dout[i] = bout[i % 3];
}

// ---------------- MFMA GEMM: C[M,N] = A[M,K] @ B[N,K]^T (+bias[N]) ----------------
template <bool BF16OUT>
__global__ __launch_bounds__(256) void k_gemm_bt(
    const unsigned short* __restrict__ A, const unsigned short* __restrict__ Bm,
    void* __restrict__ Cout, const float* __restrict__ bias, int M, int N, int Kd) {
    __shared__ unsigned short As[128 * 64];
    __shared__ unsigned short Bs[128 * 64];
    const int t = threadIdx.x;
    const int lane = t & 63;
    const int w = t >> 6, wr = w >> 1, wc = w & 1;
    const int m0 = blockIdx.x * 128, n0 = blockIdx.y * 128;
    f32x4 acc[4][4];
#pragma unroll
    for (int i = 0; i < 4; i++)
#pragma unroll
        for (int j = 0; j < 4; j++) acc[i][j] = (f32x4){0.f, 0.f, 0.f, 0.f};

    const int rowt = t >> 3, colt = (t & 7) * 8;
    for (int k0 = 0; k0 < Kd; k0 += 64) {
#pragma unroll
        for (int i = 0; i < 4; i++) {
            int row = i * 32 + rowt;
            __builtin_amdgcn_global_load_lds(
                (const __attribute__((address_space(1))) unsigned int*)(A + (size_t)(m0 + row) * Kd + k0 + colt),
                (__attribute__((address_space(3))) unsigned int*)(As + (i * 256 + t) * 8), 16, 0, 0);
            __builtin_amdgcn_global_load_lds(
                (const __attribute__((address_space(1))) unsigned int*)(Bm + (size_t)(n0 + row) * Kd + k0 + colt),
                (__attribute__((address_space(3))) unsigned int*)(Bs + (i * 256 + t) * 8), 16, 0, 0);
        }
        asm volatile("s_waitcnt vmcnt(0)" ::: "memory");
        __syncthreads();
#pragma unroll
        for (int kk = 0; kk < 2; kk++) {
            bf16x8 af[4], bfr[4];
#pragma unroll
            for (int mi = 0; mi < 4; mi++)
                af[mi] = *reinterpret_cast<const bf16x8*>(
                    As + (wr * 64 + mi * 16 + (lane & 15)) * 64 + kk * 32 + (lane >> 4) * 8);
#pragma unroll
            for (int ni = 0; ni < 4; ni++)
                bfr[ni] = *reinterpret_cast<const bf16x8*>(
                    Bs + (wc * 64 + ni * 16 + (lane & 15)) * 64 + kk * 32 + (lane >> 4) * 8);
#pragma unroll
            for (int mi = 0; mi < 4; mi++)
#pragma unroll
                for (int ni = 0; ni < 4; ni++)
                    acc[mi][ni] = __builtin_amdgcn_mfma_f32_16x16x32_bf16(af[mi], bfr[ni], acc[mi][ni], 0, 0, 0);
        }
        __syncthreads();
    }
    const int rr = (lane >> 4) * 4, cc = lane & 15;
#pragma unroll
    for (int mi = 0; mi < 4; mi++) {
#pragma unroll
        for (int ni = 0; ni < 4; ni++) {
            int col = n0 + wc * 64 + ni * 16 + cc;
            float bv = bias ? bias[col] : 0.f;
            int rowb = m0 + wr * 64 + mi * 16 + rr;
#pragma unroll
            for (int r = 0; r < 4; r++) {
                float v = acc[mi][ni][r] + bv;
                if (BF16OUT) ((unsigned short*)Cout)[(size_t)(rowb + r) * N + col] = f2bf(v);
                else         ((float*)Cout)[(size_t)(rowb + r) * N + col] = v;
            }
        }
    }
}

// ---- group barrier: 32 blocks of one bi, one counter per barrier instance ----
// No __threadfence (flushes L1/L2 -- round 6 lesson). __syncthreads drains each
// thread's outstanding stores (vmcnt0); counter + spin are agent-scope (LLC).
__device__ __forceinline__ void group_barrier(unsigned* bar) {
    __syncthreads();
    if (threadIdx.x == 0) {
        asm volatile("s_waitcnt vmcnt(0)" ::: "memory");
        __hip_atomic_fetch_add(bar, 1u, __ATOMIC_RELAXED, __HIP_MEMORY_SCOPE_AGENT);
        while (__hip_atomic_load(bar, __ATOMIC_RELAXED, __HIP_MEMORY_SCOPE_AGENT) < 32u)
            __builtin_amdgcn_s_sleep(1);
    }
    __syncthreads();
}

// ---------------- persistent decode kernel: all 32 steps, group barriers ----------------
// grid 512 x 256, 2 blocks/CU co-resident. Group = 32 blocks sharing bi = bx>>5.
// Phase A: block = (bi,hd,qt). K-slice (32KB) is staged into LDS ONCE (XOR-swizzled,
// G4: row-major [256][64] bf16 is a 32-way conflict otherwise); V + weights stay in
// L2 (per-XCD footprint ~2.8MB < 4MB after removing K). Cross-block data via LLC.
__global__ __launch_bounds__(256, 2) void k_decode(
    const unsigned short* __restrict__ K16, const unsigned short* __restrict__ V16,
    const unsigned short* __restrict__ Wq16, const float* __restrict__ bq,
    const unsigned short* __restrict__ Wf16, const unsigned short* __restrict__ Whh16,
    const float* __restrict__ dterm, const float* __restrict__ bhh,
    float* __restrict__ hb0, float* __restrict__ hb1,
    const float* __restrict__ Wout, float* __restrict__ dout,
    float* __restrict__ cross, float* __restrict__ pvP, float* __restrict__ ssumP,
    unsigned* __restrict__ bars) {
    const int t = threadIdx.x, lane = t & 63, w = t >> 6;
    const int bx = blockIdx.x;
    const int bi = bx >> 5;                 // shared by both phases
    const int hd = (bx >> 2) & 7, qt = bx & 3;   // phase A
    const int dc = bx & 31;                 // phase B: d-cols [dc*16, dc*16+16)
    unsigned* barbase = bars + bi * 64;     // 64 counters (one per barrier instance)

    __shared__ char KsB[32768];             // K slice [256 rows][8 x 16B slots], swizzled
    __shared__ float hsh[512];
    __shared__ float qsh[64];
    __shared__ float esh[256];
    __shared__ float red[256];
    __shared__ float pvred[256];
    __shared__ float ash[512];
    __shared__ float gsh[96];

    float* hcur = hb0;
    float* hnxt = hb1;
    const size_t base = (size_t)bi * (S_ * D_) + (size_t)hd * (S_ * DH_);

    // ---- one-time: stage this block's K slice into LDS (swizzled) ----
    {
        const unsigned short* kr = K16 + base + (size_t)(qt * 256 + t) * 64;
        char* krow = KsB + t * 128;
#pragma unroll
        for (int c16 = 0; c16 < 8; c16++) {
            bf16x8 kv = *reinterpret_cast<const bf16x8*>(kr + c16 * 8);
            *reinterpret_cast<bf16x8*>(krow + ((c16 ^ (t & 7)) * 16)) = kv;
        }
    }
    __syncthreads();

    for (int l = 0; l < L_; l++) {
        // ================= phase A: attention chunk =================
        hsh[t] = ld_dev(hcur + bi * 512 + t);
        hsh[256 + t] = ld_dev(hcur + bi * 512 + 256 + t);
        __syncthreads();

        // q-proj: thread (w,lane) -> col hd*64+lane, k-range [w*128, w*128+128)
        {
            float qa = 0.f;
            const unsigned short* wrow = Wq16 + (size_t)(hd * 64 + lane) * 512 + w * 128;
            const float* xk = hsh + w * 128;
#pragma unroll
            for (int kk = 0; kk < 16; kk++) {
                bf16x8 wv = *reinterpret_cast<const bf16x8*>(wrow + kk * 8);
#pragma unroll
                for (int e = 0; e < 8; e++)
                    qa += xk[kk * 8 + e] * bf2f((unsigned short)wv[e]);
            }
            red[t] = qa;
            __syncthreads();
            if (w == 0)
                qsh[lane] = (red[lane] + red[lane + 64] + red[lane + 128] + red[lane + 192]
                             + bq[hd * 64 + lane]) * (1.f / 32.f);
            __syncthreads();
        }

        // scores from LDS K (swizzled reads); max-free exp (scores O(0.3))
        const int s = qt * 256 + t;
        float sc = 0.f;
        {
            const char* krow = KsB + t * 128;
#pragma unroll
            for (int c16 = 0; c16 < 8; c16++) {
                bf16x8 kv = *reinterpret_cast<const bf16x8*>(krow + ((c16 ^ (t & 7)) * 16));
#pragma unroll
                for (int e = 0; e < 8; e++)
                    sc += qsh[c16 * 8 + e] * bf2f((unsigned short)kv[e]);
            }
        }
        float e = __expf(sc);
        esh[t] = e;
        cross[((size_t)(bi * 8 + hd) * 32 + l) * 1024 + s] = e;   // read only after kernel end
        float wsum = e;
#pragma unroll
        for (int off = 1; off < 64; off <<= 1) wsum += __shfl_xor(wsum, off);
        if (lane == 0) red[w] = wsum;
        __syncthreads();
        if (t == 0)
            st_dev(ssumP + ((size_t)(bi * 8 + hd) * 32 + l) * 4 + qt,
                   red[0] + red[1] + red[2] + red[3]);

        // PV partial: wave w covers 64 s-rows; lane -> (d-octet o, s-row srow); V from L2
        {
            const int o = lane & 7, srow = lane >> 3;
            float acc[8];
#pragma unroll
            for (int e2 = 0; e2 < 8; e2++) acc[e2] = 0.f;
            const unsigned short* vb = V16 + base + (size_t)(qt * 256 + w * 64 + srow) * 64 + o * 8;
#pragma unroll
            for (int i = 0; i < 8; i++) {
                bf16x8 vv = *reinterpret_cast<const bf16x8*>(vb + (size_t)i * 8 * 64);
                float ev = esh[w * 64 + srow + i * 8];
#pragma unroll
                for (int e2 = 0; e2 < 8; e2++)
                    acc[e2] += ev * bf2f((unsigned short)vv[e2]);
            }
#pragma unroll
            for (int off = 8; off < 64; off <<= 1)
#pragma unroll
                for (int e2 = 0; e2 < 8; e2++)
                    acc[e2] += __shfl_xor(acc[e2], off);
            if (lane < 8) {
#pragma unroll
                for (int e2 = 0; e2 < 8; e2++)
                    pvred[w * 64 + lane * 8 + e2] = acc[e2];
            }
            __syncthreads();
            if (t < 64) {
                float* pv = pvP + ((size_t)((bi * 8 + hd) * 4 + qt)) * 64;
                st_dev(pv + t, pvred[t] + pvred[64 + t] + pvred[128 + t] + pvred[192 + t]);
            }
        }

        group_barrier(barbase + 2 * l);

        // ================= phase B: gates for d-cols [dc*16, dc*16+16) =================
        // build ash[512] = normalized attention for bi (hsh still holds h[bi])
        {
            int r0 = t, r1 = t + 256;
            int h20 = r0 >> 6, d20 = r0 & 63;
            const float* sp0 = ssumP + ((size_t)(bi * 8 + h20) * 32 + l) * 4;
            float inv0 = 1.f / (ld_dev(sp0 + 0) + ld_dev(sp0 + 1) + ld_dev(sp0 + 2) + ld_dev(sp0 + 3));
            const float* pv0 = pvP + (size_t)((bi * 8 + h20) * 4) * 64 + d20;
            ash[r0] = (ld_dev(pv0 + 0) + ld_dev(pv0 + 64) + ld_dev(pv0 + 128) + ld_dev(pv0 + 192)) * inv0;
            int h21 = r1 >> 6, d21 = r1 & 63;
            const float* sp1 = ssumP + ((size_t)(bi * 8 + h21) * 32 + l) * 4;
            float inv1 = 1.f / (ld_dev(sp1 + 0) + ld_dev(sp1 + 1) + ld_dev(sp1 + 2) + ld_dev(sp1 + 3));
            const float* pv1 = pvP + (size_t)((bi * 8 + h21) * 4) * 64 + d21;
            ash[r1] = (ld_dev(pv1 + 0) + ld_dev(pv1 + 64) + ld_dev(pv1 + 128) + ld_dev(pv1 + 192)) * inv1;
        }
        __syncthreads();

        // 96 dots (16 d-cols x {gi0,gi1,gi2,gh0,gh1,gh2}), each K-split 2-way; weights L2-hot
        if (t < 192) {
            const int dotid = t >> 1, p = t & 1;
            const int src = dotid / 48, rem = dotid % 48;
            const int g = rem >> 4, di = rem & 15;
            const int j = g * 512 + dc * 16 + di;
            const unsigned short* wr2 = (src ? Whh16 : Wf16) + (size_t)j * 512 + p * 256;
            const float* x = (src ? hsh : ash) + p * 256;
            float acc = 0.f;
#pragma unroll 8
            for (int kk = 0; kk < 32; kk++) {
                bf16x8 wv = *reinterpret_cast<const bf16x8*>(wr2 + kk * 8);
#pragma unroll
                for (int e2 = 0; e2 < 8; e2++)
                    acc += x[kk * 8 + e2] * bf2f((unsigned short)wv[e2]);
            }
            red[t] = acc;
        }
        __syncthreads();
        if (t < 96) {
            const int src = t / 48, rem = t % 48;
            const int g = rem >> 4, di = rem & 15;
            const int j = g * 512 + dc * 16 + di;
            float tot = red[2 * t] + red[2 * t + 1];
            tot += src ? bhh[j] : dterm[((size_t)l * 16 + bi) * 1536 + j];
            gsh[t] = tot;   // layout: src*48 + g*16 + di == t
        }
        __syncthreads();
        if (t < 16) {
            const int d = dc * 16 + t;
            float gi0 = gsh[t], gi1 = gsh[16 + t], gi2 = gsh[32 + t];
            float gh0 = gsh[48 + t], gh1 = gsh[64 + t], gh2 = gsh[80 + t];
            float r = 1.f / (1.f + __expf(-(gi0 + gh0)));
            float z = 1.f / (1.f + __expf(-(gi1 + gh1)));
            float n = tanhf(gi2 + r * gh2);
            float hnew = (1.f - z) * n + z * hsh[d];
            st_dev(hnxt + bi * 512 + d, hnew);
            red[t]      = hnew * Wout[d];
            red[16 + t] = hnew * Wout[512 + d];
            red[32 + t] = hnew * Wout[1024 + d];
        }
        __syncthreads();
        if (t < 3) {
            float sacc = 0.f;
#pragma unroll
            for (int i2 = 0; i2 < 16; i2++) sacc += red[t * 16 + i2];
            atomicAdd(dout + ((size_t)bi * 32 + l) * 3 + t, sacc);
        }

        group_barrier(barbase + 2 * l + 1);

        float* tmp = hcur; hcur = hnxt; hnxt = tmp;
    }
}

// ---------------- deferred cross normalization: cross[b,h,l,s] /= sum ----------------
// grid 4096 x 256: full cross [16,8,32,1024]
__global__ void k_norm(float* __restrict__ cross, const float* __restrict__ ssumP) {
    int i = blockIdx.x * 256 + threadIdx.x;
    size_t b4 = (size_t)i * 4;
    int bhl = (int)(b4 >> 10);
    const float* sp = ssumP + (size_t)bhl * 4;
    float inv = 1.f / (sp[0] + sp[1] + sp[2] + sp[3]);
    float4 v = *reinterpret_cast<float4*>(cross + b4);
    v.x *= inv; v.y *= inv; v.z *= inv; v.w *= inv;
    *reinterpret_cast<float4*>(cross + b4) = v;
}

// ---------------- launch ----------------
extern "C" void kernel_launch(void* const* d_in, const int* in_sizes, int n_in,
                              void* d_out, int out_size, void* d_ws, size_t ws_size,
                              hipStream_t stream) {
    (void)in_sizes; (void)n_in; (void)out_size; (void)ws_size;
    const float* e_all  = (const float*)d_in[0];
    const float* e_last = (const float*)d_in[1];
    const float* target = (const float*)d_in[2];
    const float* Wq     = (const float*)d_in[3];
    const float* bq     = (const float*)d_in[4];
    const float* Wk     = (const float*)d_in[5];
    const float* bk     = (const float*)d_in[6];
    const float* Wv     = (const float*)d_in[7];
    const float* bv     = (const float*)d_in[8];
    const float* Wo     = (const float*)d_in[9];
    const float* bo     = (const float*)d_in[10];
    const float* W_ih   = (const float*)d_in[11];
    const float* W_hh   = (const float*)d_in[12];
    const float* b_ih   = (const float*)d_in[13];
    const float* b_hh   = (const float*)d_in[14];
    const float* W_out  = (const float*)d_in[15];
    const float* b_out  = (const float*)d_in[16];
    float* out = (float*)d_out;

    char* ws = (char*)d_ws;
    size_t off = 0;
    auto alloc = [&](size_t bytes) -> void* {
        void* p = ws + off; off += (bytes + 255) & ~(size_t)255; return p;
    };
    unsigned short* eA    = (unsigned short*)alloc(16777216);
    unsigned short* K16   = (unsigned short*)alloc(16777216);
    unsigned short* V16   = (unsigned short*)alloc(16777216);
    unsigned short* Wk16  = (unsigned short*)alloc(524288);
    unsigned short* Wv16  = (unsigned short*)alloc(524288);
    unsigned short* Wq16  = (unsigned short*)alloc(524288);
    unsigned short* Whh16 = (unsigned short*)alloc(1572864);
    unsigned short* Wih16 = (unsigned short*)alloc(1572864);
    unsigned short* WoT   = (unsigned short*)alloc(524288);
    unsigned short* Wf16  = (unsigned short*)alloc(1572864);
    float* Wf32  = (float*)alloc(3145728);
    float* bf_   = (float*)alloc(6144);
    float* Wd    = (float*)alloc(18432);
    float* dterm = (float*)alloc(3145728);
    float* hb0   = (float*)alloc(32768);
    float* hb1   = (float*)alloc(32768);
    float* pvP   = (float*)alloc(131072);   // [16][8][4][64] f32
    float* ssumP = (float*)alloc(65536);    // [16][8][32][4] f32
    unsigned* bars = (unsigned*)alloc(4096); // 16 groups x 64 barrier instances

    float* d_outputs = out;          // [16,32,3]
    float* h_fin     = out + 1536;   // [1,16,512]
    float* cross     = out + 9728;   // [16,8,32,1024]

    // one-time prep
    hipMemsetAsync(bars, 0, 4096, stream);
    k_conv<<<2048, 256, 0, stream>>>(e_all, eA, 8388608);
    k_conv<<<256, 256, 0, stream>>>(Wk, Wk16, 262144);
    k_conv<<<256, 256, 0, stream>>>(Wv, Wv16, 262144);
    k_conv<<<256, 256, 0, stream>>>(Wq, Wq16, 262144);
    k_conv<<<768, 256, 0, stream>>>(W_hh, Whh16, 786432);
    k_transpose_bf<<<dim3(16, 16), dim3(32, 8), 0, stream>>>(Wo, WoT, 512, 512);
    k_conv_wih<<<3072, 256, 0, stream>>>(W_ih, Wih16);
    k_bf_wd<<<6, 256, 0, stream>>>(W_ih, b_ih, bo, bf_, Wd);
    k_dterm<<<3072, 256, 0, stream>>>(target, Wd, bf_, dterm);
    k_gemm_bt<true><<<dim3(128, 4), 256, 0, stream>>>(eA, Wk16, K16, bk, 16384, 512, 512);
    k_gemm_bt<true><<<dim3(128, 4), 256, 0, stream>>>(eA, Wv16, V16, bv, 16384, 512, 512);
    k_gemm_bt<false><<<dim3(12, 4), 256, 0, stream>>>(Wih16, WoT, Wf32, nullptr, 1536, 512, 512);
    k_conv<<<768, 256, 0, stream>>>(Wf32, Wf16, 786432);
    k_init_out<<<6, 256, 0, stream>>>(d_outputs, b_out);
    hipMemcpyAsync(hb0, e_last, 8192 * sizeof(float), hipMemcpyDeviceToDevice, stream);

    // persistent decode: all 32 steps in one plain launch, cheap group barriers inside
    k_decode<<<512, 256, 0, stream>>>(K16, V16, Wq16, bq, Wf16, Whh16, dterm, b_hh,
                                      hb0, hb1, W_out, d_outputs, cross, pvP, ssumP, bars);

    k_norm<<<4096, 256, 0, stream>>>(cross, ssumP);
    hipMemcpyAsync(h_fin, hb0, 8192 * sizeof(float), hipMemcpyDeviceToDevice, stream);
}